// Round 7
// baseline (207.913 us; speedup 1.0000x reference)
//
#include <hip/hip_runtime.h>
#include <math.h>

#define E_ 256
#define W_ 20
#define S_ 5
#define Q_ 300
#define D_ 512
#define ALPHA_ 37.0f
#define QPAD 304
#define NT 19            // ceil(304/16) q-tiles of 16

typedef __attribute__((ext_vector_type(8))) short bf16x8;
typedef __attribute__((ext_vector_type(4))) float f32x4;
typedef __attribute__((ext_vector_type(2))) unsigned int u32x2;
typedef __attribute__((ext_vector_type(4))) unsigned int u32x4;

__device__ __forceinline__ unsigned short f2bf(float x) {
    unsigned int u = __builtin_bit_cast(unsigned int, x);
    u += 0x7fffu + ((u >> 16) & 1u);          // RNE
    return (unsigned short)(u >> 16);
}
__device__ __forceinline__ float bf2f(unsigned short h) {
    unsigned int u = ((unsigned int)h) << 16;
    return __builtin_bit_cast(float, u);
}

// LDS fragment read from s_ss: row-major [row][512 bf16], row stride 1024B,
// 16B chunks XOR-swizzled by (row&7). k0 = bf16 index, multiple of 8.
__device__ __forceinline__ bf16x8 ldfrag(const char* base, int row, int k0) {
    const int phys = (k0 >> 3) ^ (row & 7);
    return *reinterpret_cast<const bf16x8*>(base + row * 1024 + phys * 16);
}

__global__ __launch_bounds__(512, 2) void fused7(const float* __restrict__ xs,
                                                 const float* __restrict__ xq,
                                                 const float* __restrict__ temp_p,
                                                 float* __restrict__ out) {
    // 59 KB static LDS
    __shared__ __align__(16) char  s_ss[32 * 1024];   // shot_sum bf16 swz -> proto_n bf16
    __shared__ __align__(16) float s_buf[W_ * QPAD];  // -dist -> weights
    __shared__ float s_q2[QPAD];                      // ||q||^2
    __shared__ float s_m2[32];                        // ||mean||^2
    __shared__ float s_minv[32];                      // 1/||proto||
    __shared__ float s_red[8 * W_];                   // norm partials

    const int e    = blockIdx.x;
    const int tid  = threadIdx.x;
    const int lane = tid & 63;
    const int wv   = tid >> 6;
    const int ln15 = lane & 15;
    const int hi   = lane >> 4;

    const float* xse = xs + (size_t)e * (W_ * S_ * D_);
    const float* xqe = xq + (size_t)e * (Q_ * D_);
    const float  temp = *temp_p;

    // ---- P0: zero pad rows 20..31 of s_ss ----
    for (int idx = tid; idx < 12 * 64; idx += 512) {
        const int row = 20 + (idx >> 6), ch = idx & 63;
        u32x4 z = {0u, 0u, 0u, 0u};
        *reinterpret_cast<u32x4*>(s_ss + row * 1024 + ch * 16) = z;
    }
    // ---- P1: shot_sum -> s_ss bf16, float4-vectorized (r5-verified) ----
    #pragma unroll
    for (int it = 0; it < 5; ++it) {
        const int idx = it * 512 + tid;
        const int w   = idx >> 7;
        const int dq  = idx & 127;
        const float4* p0 = reinterpret_cast<const float4*>(xse + (w * S_) * D_ + dq * 4);
        float4 a = p0[0];
        #pragma unroll
        for (int s = 1; s < S_; ++s) {
            const float4 t = p0[s * (D_ / 4)];
            a.x += t.x; a.y += t.y; a.z += t.z; a.w += t.w;
        }
        u32x2 v;
        v[0] = (unsigned int)f2bf(a.x) | ((unsigned int)f2bf(a.y) << 16);
        v[1] = (unsigned int)f2bf(a.z) | ((unsigned int)f2bf(a.w) << 16);
        *reinterpret_cast<u32x2*>(s_ss + w * 1024 + (((dq >> 1) ^ (w & 7)) << 4) +
                                  (dq & 1) * 8) = v;
    }
    __syncthreads();

    // ---- PL: load Q into register fragments (wave wv owns tiles wv, wv+8, wv+16) ----
    // Fragment layout == r5's staged layout: row = tile*16+ln15, k-chunk = k*32+hi*8.
    bf16x8 qf[3][16];
    #pragma unroll
    for (int tt = 0; tt < 3; ++tt) {
        const int tile = wv + tt * 8;
        if (tile < NT) {
            const int q  = tile * 16 + ln15;
            const int qc = (q < Q_) ? q : (Q_ - 1);       // clamp tail rows
            const float* qrow = xqe + (size_t)qc * D_;
            float q2 = 0.f;
            #pragma unroll
            for (int k = 0; k < 16; ++k) {
                const int d0 = k * 32 + hi * 8;
                const float4 a = *reinterpret_cast<const float4*>(qrow + d0);
                const float4 b = *reinterpret_cast<const float4*>(qrow + d0 + 4);
                q2 += a.x * a.x + a.y * a.y + a.z * a.z + a.w * a.w
                    + b.x * b.x + b.y * b.y + b.z * b.z + b.w * b.w;
                bf16x8 v;
                v[0] = (short)f2bf(a.x); v[1] = (short)f2bf(a.y);
                v[2] = (short)f2bf(a.z); v[3] = (short)f2bf(a.w);
                v[4] = (short)f2bf(b.x); v[5] = (short)f2bf(b.y);
                v[6] = (short)f2bf(b.z); v[7] = (short)f2bf(b.w);
                qf[tt][k] = v;
            }
            // reduce ||q||^2 over the 4 hi-quarters (lanes ^16, ^32)
            q2 += __shfl_xor(q2, 16);
            q2 += __shfl_xor(q2, 32);
            if (hi == 0) s_q2[q] = q2;                    // q < 304
        }
    }

    // ---- P2: m2[w] = ||shot_mean||^2 from bf16 shot_sum ----
    for (int w = wv; w < W_; w += 8) {
        bf16x8 v = *reinterpret_cast<const bf16x8*>(s_ss + w * 1024 + ((lane ^ (w & 7)) << 4));
        float p = 0.f;
        #pragma unroll
        for (int j = 0; j < 8; ++j) { float f = bf2f((unsigned short)v[j]); p += f * f; }
        #pragma unroll
        for (int off = 32; off; off >>= 1) p += __shfl_xor(p, off);
        if (lane == 0) s_m2[w] = p * (1.f / (S_ * S_));
    }
    __syncthreads();

    // ---- P3: dist MFMA, no barriers: per wave, per owned tile, both w-tiles ----
    #pragma unroll
    for (int tt = 0; tt < 3; ++tt) {
        const int tile = wv + tt * 8;
        if (tile < NT) {
            f32x4 acc0 = {0.f, 0.f, 0.f, 0.f};
            f32x4 acc1 = {0.f, 0.f, 0.f, 0.f};
            #pragma unroll
            for (int k = 0; k < 16; ++k) {
                const bf16x8 a0 = ldfrag(s_ss, ln15,      k * 32 + hi * 8);
                const bf16x8 a1 = ldfrag(s_ss, 16 + ln15, k * 32 + hi * 8);
                acc0 = __builtin_amdgcn_mfma_f32_16x16x32_bf16(a0, qf[tt][k], acc0, 0, 0, 0);
                acc1 = __builtin_amdgcn_mfma_f32_16x16x32_bf16(a1, qf[tt][k], acc1, 0, 0, 0);
            }
            // C/D: col(N=q)=ln15, row(M=w)=hi*4+r  (r3 HW-verified)
            const int q = tile * 16 + ln15;
            if (q < Q_) {
                const float q2v = s_q2[q];
                #pragma unroll
                for (int r = 0; r < 4; ++r) {
                    const int w0 = hi * 4 + r;            // w-tile 0: always < 16
                    float d2 = s_m2[w0] + q2v - 0.4f * acc0[r];
                    s_buf[w0 * QPAD + q] = -sqrtf(fmaxf(d2, 0.f));
                    const int w1 = 16 + hi * 4 + r;       // w-tile 1: mask < 20
                    if (w1 < W_) {
                        float e2 = s_m2[w1] + q2v - 0.4f * acc1[r];
                        s_buf[w1 * QPAD + q] = -sqrtf(fmaxf(e2, 0.f));
                    }
                }
            }
        }
    }
    __syncthreads();

    // ---- P4: softmax over q per w ----
    for (int w = wv; w < W_; w += 8) {
        float mx = -1e30f;
        for (int q = lane; q < Q_; q += 64) mx = fmaxf(mx, s_buf[w * QPAD + q]);
        #pragma unroll
        for (int off = 32; off; off >>= 1) mx = fmaxf(mx, __shfl_xor(mx, off));
        float sm = 0.f;
        for (int q = lane; q < Q_; q += 64) {
            float ex = __expf(s_buf[w * QPAD + q] - mx);
            s_buf[w * QPAD + q] = ex;
            sm += ex;
        }
        #pragma unroll
        for (int off = 32; off; off >>= 1) sm += __shfl_xor(sm, off);
        const float inv = 1.f / sm;
        for (int q = lane; q < Q_; q += 64) s_buf[w * QPAD + q] *= inv;
    }
    __syncthreads();

    // ---- P5: pooled (d = tid, f32, L3-warm global reads) + proto + norms ----
    {
        float pr[W_];
        #pragma unroll
        for (int w = 0; w < W_; ++w) pr[w] = 0.f;
        for (int q0 = 0; q0 < Q_; q0 += 4) {
            const float qv0 = xqe[(q0 + 0) * D_ + tid];
            const float qv1 = xqe[(q0 + 1) * D_ + tid];
            const float qv2 = xqe[(q0 + 2) * D_ + tid];
            const float qv3 = xqe[(q0 + 3) * D_ + tid];
            #pragma unroll
            for (int w = 0; w < W_; ++w) {
                const float4 wt = *reinterpret_cast<const float4*>(&s_buf[w * QPAD + q0]);
                pr[w] += wt.x * qv0 + wt.y * qv1 + wt.z * qv2 + wt.w * qv3;
            }
        }
        const int chb = tid >> 3;
        #pragma unroll
        for (int w = 0; w < W_; ++w) {
            unsigned short h =
                *(unsigned short*)(s_ss + w * 1024 + ((chb ^ (w & 7)) << 4) + (tid & 7) * 2);
            pr[w] = (bf2f(h) + ALPHA_ * pr[w]) * (1.f / (S_ + ALPHA_));
        }
        #pragma unroll
        for (int w = 0; w < W_; ++w) {
            float p = pr[w] * pr[w];
            #pragma unroll
            for (int off = 32; off; off >>= 1) p += __shfl_xor(p, off);
            if (lane == 0) s_red[wv * W_ + w] = p;
        }
        __syncthreads();
        if (tid < W_) {
            float p = 0.f;
            #pragma unroll
            for (int k = 0; k < 8; ++k) p += s_red[k * W_ + tid];
            s_minv[tid] = 1.f / fmaxf(sqrtf(p), 1e-12f);
        }
        __syncthreads();
        #pragma unroll
        for (int w = 0; w < W_; ++w) {
            *(unsigned short*)(s_ss + w * 1024 + ((chb ^ (w & 7)) << 4) + (tid & 7) * 2) =
                f2bf(pr[w] * s_minv[w]);
        }
        __syncthreads();
    }

    // ---- P6: logits MFMA, no barriers: A = qf (in-reg), B = proto_n (LDS) ----
    const size_t eoff = (size_t)e * (Q_ * W_);
    #pragma unroll
    for (int tt = 0; tt < 3; ++tt) {
        const int tile = wv + tt * 8;
        if (tile < NT) {
            f32x4 acc0 = {0.f, 0.f, 0.f, 0.f};
            f32x4 acc1 = {0.f, 0.f, 0.f, 0.f};
            #pragma unroll
            for (int k = 0; k < 16; ++k) {
                const bf16x8 b0 = ldfrag(s_ss, ln15,      k * 32 + hi * 8);
                const bf16x8 b1 = ldfrag(s_ss, 16 + ln15, k * 32 + hi * 8);
                acc0 = __builtin_amdgcn_mfma_f32_16x16x32_bf16(qf[tt][k], b0, acc0, 0, 0, 0);
                acc1 = __builtin_amdgcn_mfma_f32_16x16x32_bf16(qf[tt][k], b1, acc1, 0, 0, 0);
            }
            // C/D: row(M=q)=hi*4+r, col(N=w)=ln15
            #pragma unroll
            for (int r = 0; r < 4; ++r) {
                const int q = tile * 16 + hi * 4 + r;
                if (q < Q_) {
                    const float scale = temp / fmaxf(sqrtf(s_q2[q]), 1e-12f);
                    out[eoff + q * W_ + ln15] = scale * acc0[r];      // w = ln15 < 16
                    const int w1 = 16 + ln15;                          // mask < 20
                    if (w1 < W_) out[eoff + q * W_ + w1] = scale * acc1[r];
                }
            }
        }
    }
}

extern "C" void kernel_launch(void* const* d_in, const int* in_sizes, int n_in,
                              void* d_out, int out_size, void* d_ws, size_t ws_size,
                              hipStream_t stream) {
    const float* xs = (const float*)d_in[0];
    const float* xq = (const float*)d_in[1];
    const float* tp = (const float*)d_in[2];
    fused7<<<E_, 512, 0, stream>>>(xs, xq, tp, (float*)d_out);
}

// Round 8
// 150.740 us; speedup vs baseline: 1.3793x; 1.3793x over previous
//
#include <hip/hip_runtime.h>
#include <math.h>

#define E_ 256
#define W_ 20
#define S_ 5
#define Q_ 300
#define D_ 512
#define ALPHA_ 37.0f
#define QPAD 304
#define NT 19            // ceil(304/16) q-tiles of 16

typedef __attribute__((ext_vector_type(8))) short bf16x8;
typedef __attribute__((ext_vector_type(4))) float f32x4;
typedef __attribute__((ext_vector_type(2))) unsigned int u32x2;
typedef __attribute__((ext_vector_type(4))) unsigned int u32x4;

__device__ __forceinline__ unsigned short f2bf(float x) {
    unsigned int u = __builtin_bit_cast(unsigned int, x);
    u += 0x7fffu + ((u >> 16) & 1u);          // RNE
    return (unsigned short)(u >> 16);
}
__device__ __forceinline__ float bf2f(unsigned short h) {
    unsigned int u = ((unsigned int)h) << 16;
    return __builtin_bit_cast(float, u);
}

// LDS fragment read from s_ss: row-major [row][512 bf16], row stride 1024B,
// 16B chunks XOR-swizzled by (row&7). k0 = bf16 index, multiple of 8.
__device__ __forceinline__ bf16x8 ldfrag(const char* base, int row, int k0) {
    const int phys = (k0 >> 3) ^ (row & 7);
    return *reinterpret_cast<const bf16x8*>(base + row * 1024 + phys * 16);
}

// Load one 16-row Q tile fragment set from GLOBAL into registers (transient).
// Fragment layout (r5/r7-verified): row = tile*16+ln15, k-chunk = k*32+hi*8.
__device__ __forceinline__ float qtile_load(const float* __restrict__ xqe,
                                            int tile, int ln15, int hi,
                                            bf16x8* qf) {
    const int q  = tile * 16 + ln15;
    const int qc = (q < Q_) ? q : (Q_ - 1);           // clamp tail rows
    const float* qrow = xqe + (size_t)qc * D_;
    float q2 = 0.f;
    #pragma unroll
    for (int k = 0; k < 16; ++k) {
        const int d0 = k * 32 + hi * 8;
        const float4 a = *reinterpret_cast<const float4*>(qrow + d0);
        const float4 b = *reinterpret_cast<const float4*>(qrow + d0 + 4);
        q2 += a.x * a.x + a.y * a.y + a.z * a.z + a.w * a.w
            + b.x * b.x + b.y * b.y + b.z * b.z + b.w * b.w;
        bf16x8 v;
        v[0] = (short)f2bf(a.x); v[1] = (short)f2bf(a.y);
        v[2] = (short)f2bf(a.z); v[3] = (short)f2bf(a.w);
        v[4] = (short)f2bf(b.x); v[5] = (short)f2bf(b.y);
        v[6] = (short)f2bf(b.z); v[7] = (short)f2bf(b.w);
        qf[k] = v;
    }
    // full ||q||^2 in every lane after folding the 4 hi-quarters
    q2 += __shfl_xor(q2, 16);
    q2 += __shfl_xor(q2, 32);
    return q2;
}

__global__ __launch_bounds__(1024) void fused8(const float* __restrict__ xs,
                                               const float* __restrict__ xq,
                                               const float* __restrict__ temp_p,
                                               float* __restrict__ out) {
    // 59 KB static LDS
    __shared__ __align__(16) char  s_ss[32 * 1024];   // shot_sum bf16 swz -> proto_n bf16
    __shared__ __align__(16) float s_buf[W_ * QPAD];  // -dist -> weights
    __shared__ float s_q2[320];                       // ||q||^2
    __shared__ float s_m2[32];                        // ||mean||^2
    __shared__ float s_minv[32];                      // 1/||proto||
    __shared__ float s_red[8 * W_];                   // norm partials

    const int e    = blockIdx.x;
    const int tid  = threadIdx.x;                     // 0..1023
    const int lane = tid & 63;
    const int wv   = tid >> 6;                        // wave 0..15
    const int ln15 = lane & 15;
    const int hi   = lane >> 4;

    const float* xse = xs + (size_t)e * (W_ * S_ * D_);
    const float* xqe = xq + (size_t)e * (Q_ * D_);
    const float  temp = *temp_p;

    // ---- P0: zero pad rows 20..31 of s_ss ----
    if (tid < 12 * 64) {
        const int row = 20 + (tid >> 6), ch = tid & 63;
        u32x4 z = {0u, 0u, 0u, 0u};
        *reinterpret_cast<u32x4*>(s_ss + row * 1024 + ch * 16) = z;
    }
    // ---- P1: shot_sum -> s_ss bf16, float4-vectorized (r5-verified) ----
    #pragma unroll
    for (int it = 0; it < 3; ++it) {
        const int idx = it * 1024 + tid;
        if (idx < W_ * 128) {
            const int w  = idx >> 7;
            const int dq = idx & 127;
            const float4* p0 = reinterpret_cast<const float4*>(xse + (w * S_) * D_ + dq * 4);
            float4 a = p0[0];
            #pragma unroll
            for (int s = 1; s < S_; ++s) {
                const float4 t = p0[s * (D_ / 4)];
                a.x += t.x; a.y += t.y; a.z += t.z; a.w += t.w;
            }
            u32x2 v;
            v[0] = (unsigned int)f2bf(a.x) | ((unsigned int)f2bf(a.y) << 16);
            v[1] = (unsigned int)f2bf(a.z) | ((unsigned int)f2bf(a.w) << 16);
            *reinterpret_cast<u32x2*>(s_ss + w * 1024 + (((dq >> 1) ^ (w & 7)) << 4) +
                                      (dq & 1) * 8) = v;
        }
    }
    __syncthreads();

    // ---- P3 pass 0 loads issued EARLY (hide HBM latency under P2) ----
    bf16x8 qf[16];
    float q2r = qtile_load(xqe, wv, ln15, hi, qf);
    {
        const int q = wv * 16 + ln15;
        if (hi == 0) s_q2[q] = q2r;                   // q <= 255 here
    }

    // ---- P2: m2[w] = ||shot_mean||^2 from bf16 shot_sum ----
    for (int w = wv; w < W_; w += 16) {
        bf16x8 v = *reinterpret_cast<const bf16x8*>(s_ss + w * 1024 + ((lane ^ (w & 7)) << 4));
        float p = 0.f;
        #pragma unroll
        for (int j = 0; j < 8; ++j) { float f = bf2f((unsigned short)v[j]); p += f * f; }
        #pragma unroll
        for (int off = 32; off; off >>= 1) p += __shfl_xor(p, off);
        if (lane == 0) s_m2[w] = p * (1.f / (S_ * S_));
    }
    __syncthreads();

    // ---- P3: dist MFMA; wave wv does tile wv, waves 0-2 also tiles 16-18 ----
    #pragma unroll
    for (int pass = 0; pass < 2; ++pass) {
        const int tile = pass ? (16 + wv) : wv;
        if (pass && tile >= NT) break;
        if (pass) {
            q2r = qtile_load(xqe, tile, ln15, hi, qf);
            const int q = tile * 16 + ln15;
            if (hi == 0) s_q2[q] = q2r;               // q <= 303 < 320
        }
        f32x4 acc0 = {0.f, 0.f, 0.f, 0.f};
        f32x4 acc1 = {0.f, 0.f, 0.f, 0.f};
        #pragma unroll
        for (int k = 0; k < 16; ++k) {
            const bf16x8 a0 = ldfrag(s_ss, ln15,      k * 32 + hi * 8);
            const bf16x8 a1 = ldfrag(s_ss, 16 + ln15, k * 32 + hi * 8);
            acc0 = __builtin_amdgcn_mfma_f32_16x16x32_bf16(a0, qf[k], acc0, 0, 0, 0);
            acc1 = __builtin_amdgcn_mfma_f32_16x16x32_bf16(a1, qf[k], acc1, 0, 0, 0);
        }
        // C/D (HW-verified r3): col(N=q)=ln15, row(M=w)=hi*4+r
        const int q = tile * 16 + ln15;
        if (q < Q_) {
            #pragma unroll
            for (int r = 0; r < 4; ++r) {
                const int w0 = hi * 4 + r;
                float d2 = s_m2[w0] + q2r - 0.4f * acc0[r];
                s_buf[w0 * QPAD + q] = -sqrtf(fmaxf(d2, 0.f));
                const int w1 = 16 + hi * 4 + r;
                if (w1 < W_) {
                    float e2 = s_m2[w1] + q2r - 0.4f * acc1[r];
                    s_buf[w1 * QPAD + q] = -sqrtf(fmaxf(e2, 0.f));
                }
            }
        }
    }
    __syncthreads();

    // ---- P4: softmax over q per w ----
    for (int w = wv; w < W_; w += 16) {
        float mx = -1e30f;
        for (int q = lane; q < Q_; q += 64) mx = fmaxf(mx, s_buf[w * QPAD + q]);
        #pragma unroll
        for (int off = 32; off; off >>= 1) mx = fmaxf(mx, __shfl_xor(mx, off));
        float sm = 0.f;
        for (int q = lane; q < Q_; q += 64) {
            float ex = __expf(s_buf[w * QPAD + q] - mx);
            s_buf[w * QPAD + q] = ex;
            sm += ex;
        }
        #pragma unroll
        for (int off = 32; off; off >>= 1) sm += __shfl_xor(sm, off);
        const float inv = 1.f / sm;
        for (int q = lane; q < Q_; q += 64) s_buf[w * QPAD + q] *= inv;
    }
    __syncthreads();

    // ---- P5: pooled + proto + norms + proto_n (waves 0-7; barriers flattened) ----
    {
        float pr[W_];
        if (tid < 512) {
            #pragma unroll
            for (int w = 0; w < W_; ++w) pr[w] = 0.f;
            for (int q0 = 0; q0 < Q_; q0 += 4) {
                const float qv0 = xqe[(q0 + 0) * D_ + tid];
                const float qv1 = xqe[(q0 + 1) * D_ + tid];
                const float qv2 = xqe[(q0 + 2) * D_ + tid];
                const float qv3 = xqe[(q0 + 3) * D_ + tid];
                #pragma unroll
                for (int w = 0; w < W_; ++w) {
                    const float4 wt = *reinterpret_cast<const float4*>(&s_buf[w * QPAD + q0]);
                    pr[w] += wt.x * qv0 + wt.y * qv1 + wt.z * qv2 + wt.w * qv3;
                }
            }
            const int chb = tid >> 3;
            #pragma unroll
            for (int w = 0; w < W_; ++w) {
                unsigned short h =
                    *(unsigned short*)(s_ss + w * 1024 + ((chb ^ (w & 7)) << 4) + (tid & 7) * 2);
                pr[w] = (bf2f(h) + ALPHA_ * pr[w]) * (1.f / (S_ + ALPHA_));
            }
            #pragma unroll
            for (int w = 0; w < W_; ++w) {
                float p = pr[w] * pr[w];
                #pragma unroll
                for (int off = 32; off; off >>= 1) p += __shfl_xor(p, off);
                if (lane == 0) s_red[wv * W_ + w] = p;
            }
        }
        __syncthreads();
        if (tid < W_) {
            float p = 0.f;
            #pragma unroll
            for (int k = 0; k < 8; ++k) p += s_red[k * W_ + tid];
            s_minv[tid] = 1.f / fmaxf(sqrtf(p), 1e-12f);
        }
        __syncthreads();
        if (tid < 512) {
            const int chb = tid >> 3;
            #pragma unroll
            for (int w = 0; w < W_; ++w) {
                *(unsigned short*)(s_ss + w * 1024 + ((chb ^ (w & 7)) << 4) + (tid & 7) * 2) =
                    f2bf(pr[w] * s_minv[w]);
            }
        }
        __syncthreads();
    }

    // ---- P6: logits MFMA; per-tile Q reload (L3-warm); direct store ----
    const size_t eoff = (size_t)e * (Q_ * W_);
    #pragma unroll
    for (int pass = 0; pass < 2; ++pass) {
        const int tile = pass ? (16 + wv) : wv;
        if (pass && tile >= NT) break;
        (void)qtile_load(xqe, tile, ln15, hi, qf);
        f32x4 acc0 = {0.f, 0.f, 0.f, 0.f};
        f32x4 acc1 = {0.f, 0.f, 0.f, 0.f};
        #pragma unroll
        for (int k = 0; k < 16; ++k) {
            const bf16x8 b0 = ldfrag(s_ss, ln15,      k * 32 + hi * 8);
            const bf16x8 b1 = ldfrag(s_ss, 16 + ln15, k * 32 + hi * 8);
            acc0 = __builtin_amdgcn_mfma_f32_16x16x32_bf16(qf[k], b0, acc0, 0, 0, 0);
            acc1 = __builtin_amdgcn_mfma_f32_16x16x32_bf16(qf[k], b1, acc1, 0, 0, 0);
        }
        // C/D: row(M=q)=hi*4+r, col(N=w)=ln15
        #pragma unroll
        for (int r = 0; r < 4; ++r) {
            const int q = tile * 16 + hi * 4 + r;
            if (q < Q_) {
                const float scale = temp / fmaxf(sqrtf(s_q2[q]), 1e-12f);
                out[eoff + q * W_ + ln15] = scale * acc0[r];      // w = ln15 < 16
                const int w1 = 16 + ln15;
                if (w1 < W_) out[eoff + q * W_ + w1] = scale * acc1[r];
            }
        }
    }
}

extern "C" void kernel_launch(void* const* d_in, const int* in_sizes, int n_in,
                              void* d_out, int out_size, void* d_ws, size_t ws_size,
                              hipStream_t stream) {
    const float* xs = (const float*)d_in[0];
    const float* xq = (const float*)d_in[1];
    const float* tp = (const float*)d_in[2];
    fused8<<<E_, 1024, 0, stream>>>(xs, xq, tp, (float*)d_out);
}

// Round 9
// 122.337 us; speedup vs baseline: 1.6995x; 1.2322x over previous
//
#include <hip/hip_runtime.h>
#include <math.h>

#define E_ 256
#define W_ 20
#define S_ 5
#define Q_ 300
#define D_ 512
#define ALPHA_ 37.0f
#define QCH 32
#define NCH 10           // chunks: 9x32 + 12
#define QPAD 304

typedef __attribute__((ext_vector_type(8))) short bf16x8;
typedef __attribute__((ext_vector_type(4))) float f32x4;
typedef __attribute__((ext_vector_type(2))) unsigned int u32x2;
typedef __attribute__((ext_vector_type(4))) unsigned int u32x4;

// dynamic LDS layout (bytes) — 79744 B => 2 blocks/CU (2x79872 granule-rounded <= 160K)
#define OFF_SS   0         // 20 rows x 1024B : shot_sum bf16 swz -> proto_n bf16
#define OFF_XQ   20480     // 32 rows x 1024B : xq chunk bf16 swz
#define OFF_BUF  53248     // f32 [20][304]   : -dist -> weights
#define OFF_Q2   77568     // f32 [320]       : ||q||^2 (chunk-9 staging writes 288..319)
#define OFF_M2   78848     // f32 [32]        : ||mean||^2
#define OFF_MINV 78976     // f32 [32]        : 1/||proto||
#define OFF_RED  79104     // f32 [8][20]     : norm partials
#define LDS_BYTES 79744

__device__ __forceinline__ unsigned short f2bf(float x) {
    unsigned int u = __builtin_bit_cast(unsigned int, x);
    u += 0x7fffu + ((u >> 16) & 1u);          // RNE
    return (unsigned short)(u >> 16);
}
__device__ __forceinline__ float bf2f(unsigned short h) {
    unsigned int u = ((unsigned int)h) << 16;
    return __builtin_bit_cast(float, u);
}

// MFMA fragment read: row-major [row][512 bf16], row stride 1024B,
// 16B chunks XOR-swizzled by (row&7). k0 = bf16 index, multiple of 8.
__device__ __forceinline__ bf16x8 ldfrag(const char* base, int row, int k0) {
    const int phys = (k0 >> 3) ^ (row & 7);
    return *reinterpret_cast<const bf16x8*>(base + row * 1024 + phys * 16);
}

// ---- staging: 32-q chunks; thread (qr=tid>>4, i=tid&15), 4 x 16B pairs ----
__device__ __forceinline__ void stage_load(const float4* xq4, int c, int qcount,
                                           int tid, float4* r) {
    const int qr = tid >> 4;                              // 0..31
    const int i  = tid & 15;
    const int qg = c * QCH + ((qr < qcount) ? qr : 0);    // clamp to in-bounds row
    const float4* row4 = xq4 + (size_t)qg * (D_ / 4);
    #pragma unroll
    for (int j = 0; j < 4; ++j) {
        const int ch = i + 16 * j;                        // 16B chunk 0..63
        r[2 * j]     = row4[2 * ch];
        r[2 * j + 1] = row4[2 * ch + 1];
    }
}

template <bool WQ2>
__device__ __forceinline__ void stage_write(const float4* r, char* s_xq, float* s_q2,
                                            int c, int qcount, int tid) {
    const int qr = tid >> 4;
    const int i  = tid & 15;
    const bool valid = qr < qcount;
    float q2 = 0.f;
    #pragma unroll
    for (int j = 0; j < 4; ++j) {
        const int ch = i + 16 * j;
        float4 a = valid ? r[2 * j]     : make_float4(0.f, 0.f, 0.f, 0.f);
        float4 b = valid ? r[2 * j + 1] : make_float4(0.f, 0.f, 0.f, 0.f);
        if (WQ2) {
            q2 += a.x * a.x + a.y * a.y + a.z * a.z + a.w * a.w
                + b.x * b.x + b.y * b.y + b.z * b.z + b.w * b.w;
        }
        u32x4 v;
        v[0] = (unsigned int)f2bf(a.x) | ((unsigned int)f2bf(a.y) << 16);
        v[1] = (unsigned int)f2bf(a.z) | ((unsigned int)f2bf(a.w) << 16);
        v[2] = (unsigned int)f2bf(b.x) | ((unsigned int)f2bf(b.y) << 16);
        v[3] = (unsigned int)f2bf(b.z) | ((unsigned int)f2bf(b.w) << 16);
        *reinterpret_cast<u32x4*>(s_xq + qr * 1024 + ((ch ^ (qr & 7)) << 4)) = v;
    }
    if (WQ2) {
        q2 += __shfl_xor(q2, 1);
        q2 += __shfl_xor(q2, 2);
        q2 += __shfl_xor(q2, 4);
        q2 += __shfl_xor(q2, 8);
        if (i == 0) s_q2[c * QCH + qr] = valid ? q2 : 0.f;  // up to 319; sized 320
    }
}

__global__ __launch_bounds__(512, 4) void fused9(const float* __restrict__ xs,
                                                 const float* __restrict__ xq,
                                                 const float* __restrict__ temp_p,
                                                 float* __restrict__ out) {
    extern __shared__ char smem[];
    char*  s_ss   = smem + OFF_SS;
    char*  s_xq   = smem + OFF_XQ;
    float* s_buf  = (float*)(smem + OFF_BUF);
    float* s_q2   = (float*)(smem + OFF_Q2);
    float* s_m2   = (float*)(smem + OFF_M2);
    float* s_minv = (float*)(smem + OFF_MINV);
    float* s_red  = (float*)(smem + OFF_RED);

    const int e    = blockIdx.x;
    const int tid  = threadIdx.x;
    const int lane = tid & 63;
    const int wv   = tid >> 6;
    const int ln15 = lane & 15;
    const int hi   = lane >> 4;

    const float*  xse = xs + (size_t)e * (W_ * S_ * D_);
    const float*  xqe = xq + (size_t)e * (Q_ * D_);
    const float4* xq4 = (const float4*)xqe;
    const float   temp = *temp_p;

    float4 buf[8];

    // prefetch P3 chunk 0 (hides under P1)
    stage_load(xq4, 0, QCH, tid, buf);

    // ---- P1: shot_sum -> s_ss bf16, float4-vectorized (r5-verified) ----
    #pragma unroll
    for (int it = 0; it < 5; ++it) {
        const int idx = it * 512 + tid;           // 2560 = 20*128 exact
        const int w   = idx >> 7;
        const int dq  = idx & 127;
        const float4* p0 = reinterpret_cast<const float4*>(xse + (w * S_) * D_ + dq * 4);
        float4 a = p0[0];
        #pragma unroll
        for (int s = 1; s < S_; ++s) {
            const float4 t = p0[s * (D_ / 4)];
            a.x += t.x; a.y += t.y; a.z += t.z; a.w += t.w;
        }
        u32x2 v;
        v[0] = (unsigned int)f2bf(a.x) | ((unsigned int)f2bf(a.y) << 16);
        v[1] = (unsigned int)f2bf(a.z) | ((unsigned int)f2bf(a.w) << 16);
        *reinterpret_cast<u32x2*>(s_ss + w * 1024 + (((dq >> 1) ^ (w & 7)) << 4) +
                                  (dq & 1) * 8) = v;
    }
    __syncthreads();

    // ---- P2: m2[w] = ||shot_mean||^2 from bf16 shot_sum ----
    for (int w = wv; w < W_; w += 8) {
        bf16x8 v = *reinterpret_cast<const bf16x8*>(s_ss + w * 1024 + ((lane ^ (w & 7)) << 4));
        float p = 0.f;
        #pragma unroll
        for (int j = 0; j < 8; ++j) { float f = bf2f((unsigned short)v[j]); p += f * f; }
        #pragma unroll
        for (int off = 32; off; off >>= 1) p += __shfl_xor(p, off);
        if (lane == 0) s_m2[w] = p * (1.f / (S_ * S_));
    }
    __syncthreads();

    // ---- P3: dist via MFMA per 32-q chunk ----
    // w-tiles overlap: tile0 rows 0-15, tile1 rows 4-19 (dup writes identical) -> no pad rows
    for (int c = 0; c < NCH; ++c) {
        const int qcount = (c == NCH - 1) ? (Q_ - (NCH - 1) * QCH) : QCH;
        stage_write<true>(buf, s_xq, s_q2, c, qcount, tid);
        __syncthreads();
        if (c + 1 < NCH)
            stage_load(xq4, c + 1, (c + 2 == NCH) ? (Q_ - (NCH - 1) * QCH) : QCH, tid, buf);

        if (wv < 4) {
            const int wtile = wv >> 1, qtile = wv & 1;
            f32x4 acc = {0.f, 0.f, 0.f, 0.f};
            const int arow = wtile * 4 + ln15;        // w row (M side): base 0 or 4
            const int brow = qtile * 16 + ln15;       // q row (N side)
            #pragma unroll
            for (int k = 0; k < 16; ++k) {
                bf16x8 a = ldfrag(s_ss, arow, k * 32 + hi * 8);
                bf16x8 b = ldfrag(s_xq, brow, k * 32 + hi * 8);
                acc = __builtin_amdgcn_mfma_f32_16x16x32_bf16(a, b, acc, 0, 0, 0);
            }
            // C/D (HW-verified r3): col(N=q)=ln15, row(M=w)=hi*4+r
            const int qloc = qtile * 16 + ln15;
            if (qloc < qcount) {
                const int qg = c * QCH + qloc;
                const float q2v = s_q2[qg];
                #pragma unroll
                for (int r = 0; r < 4; ++r) {
                    const int w = wtile * 4 + hi * 4 + r;   // 0-15 / 4-19, always < 20
                    float d2 = s_m2[w] + q2v - 0.4f * acc[r];
                    s_buf[w * QPAD + qg] = -sqrtf(fmaxf(d2, 0.f));
                }
            }
        }
        __syncthreads();
    }

    // ---- P4: softmax over q per w ----
    for (int w = wv; w < W_; w += 8) {
        float mx = -1e30f;
        for (int q = lane; q < Q_; q += 64) mx = fmaxf(mx, s_buf[w * QPAD + q]);
        #pragma unroll
        for (int off = 32; off; off >>= 1) mx = fmaxf(mx, __shfl_xor(mx, off));
        float sm = 0.f;
        for (int q = lane; q < Q_; q += 64) {
            float ex = __expf(s_buf[w * QPAD + q] - mx);
            s_buf[w * QPAD + q] = ex;
            sm += ex;
        }
        #pragma unroll
        for (int off = 32; off; off >>= 1) sm += __shfl_xor(sm, off);
        const float inv = 1.f / sm;
        for (int q = lane; q < Q_; q += 64) s_buf[w * QPAD + q] *= inv;
    }
    __syncthreads();

    // prefetch P6 chunk 0 (hides under P5)
    stage_load(xq4, 0, QCH, tid, buf);

    // ---- P5: pooled (d = tid) + proto + norms + proto_n -> s_ss bf16 ----
    {
        float pr[W_];
        #pragma unroll
        for (int w = 0; w < W_; ++w) pr[w] = 0.f;
        for (int q0 = 0; q0 < Q_; q0 += 4) {
            const float qv0 = xqe[(q0 + 0) * D_ + tid];
            const float qv1 = xqe[(q0 + 1) * D_ + tid];
            const float qv2 = xqe[(q0 + 2) * D_ + tid];
            const float qv3 = xqe[(q0 + 3) * D_ + tid];
            #pragma unroll
            for (int w = 0; w < W_; ++w) {
                const float4 wt = *reinterpret_cast<const float4*>(&s_buf[w * QPAD + q0]);
                pr[w] += wt.x * qv0 + wt.y * qv1 + wt.z * qv2 + wt.w * qv3;
            }
        }
        const int chb = tid >> 3;
        #pragma unroll
        for (int w = 0; w < W_; ++w) {
            unsigned short h =
                *(unsigned short*)(s_ss + w * 1024 + ((chb ^ (w & 7)) << 4) + (tid & 7) * 2);
            pr[w] = (bf2f(h) + ALPHA_ * pr[w]) * (1.f / (S_ + ALPHA_));
        }
        #pragma unroll
        for (int w = 0; w < W_; ++w) {
            float p = pr[w] * pr[w];
            #pragma unroll
            for (int off = 32; off; off >>= 1) p += __shfl_xor(p, off);
            if (lane == 0) s_red[wv * W_ + w] = p;
        }
        __syncthreads();
        if (tid < W_) {
            float p = 0.f;
            #pragma unroll
            for (int k = 0; k < 8; ++k) p += s_red[k * W_ + tid];
            s_minv[tid] = 1.f / fmaxf(sqrtf(p), 1e-12f);
        }
        __syncthreads();
        #pragma unroll
        for (int w = 0; w < W_; ++w) {
            *(unsigned short*)(s_ss + w * 1024 + ((chb ^ (w & 7)) << 4) + (tid & 7) * 2) =
                f2bf(pr[w] * s_minv[w]);
        }
        __syncthreads();
    }

    // ---- P6: logits via MFMA per 32-q chunk; direct global store ----
    const size_t eoff = (size_t)e * (Q_ * W_);
    for (int c = 0; c < NCH; ++c) {
        const int qcount = (c == NCH - 1) ? (Q_ - (NCH - 1) * QCH) : QCH;
        stage_write<false>(buf, s_xq, s_q2, c, qcount, tid);
        __syncthreads();
        if (c + 1 < NCH)
            stage_load(xq4, c + 1, (c + 2 == NCH) ? (Q_ - (NCH - 1) * QCH) : QCH, tid, buf);

        if (wv < 4) {
            const int qtile = wv >> 1, wtile = wv & 1;
            f32x4 acc = {0.f, 0.f, 0.f, 0.f};
            const int arow = qtile * 16 + ln15;       // q row (M side)
            const int brow = wtile * 4 + ln15;        // w row (N side): base 0 or 4
            #pragma unroll
            for (int k = 0; k < 16; ++k) {
                bf16x8 a = ldfrag(s_xq, arow, k * 32 + hi * 8);
                bf16x8 b = ldfrag(s_ss, brow, k * 32 + hi * 8);
                acc = __builtin_amdgcn_mfma_f32_16x16x32_bf16(a, b, acc, 0, 0, 0);
            }
            // C/D: row(M=q)=hi*4+r, col(N=w)=ln15
            const int w = wtile * 4 + ln15;           // 0-15 / 4-19, always < 20
            #pragma unroll
            for (int r = 0; r < 4; ++r) {
                const int qloc = qtile * 16 + hi * 4 + r;
                if (qloc < qcount) {
                    const int qg = c * QCH + qloc;
                    const float scale = temp / fmaxf(sqrtf(s_q2[qg]), 1e-12f);
                    out[eoff + qg * W_ + w] = scale * acc[r];
                }
            }
        }
        __syncthreads();
    }
}

extern "C" void kernel_launch(void* const* d_in, const int* in_sizes, int n_in,
                              void* d_out, int out_size, void* d_ws, size_t ws_size,
                              hipStream_t stream) {
    const float* xs = (const float*)d_in[0];
    const float* xq = (const float*)d_in[1];
    const float* tp = (const float*)d_in[2];
    hipFuncSetAttribute(reinterpret_cast<const void*>(fused9),
                        hipFuncAttributeMaxDynamicSharedMemorySize, LDS_BYTES);
    fused9<<<E_, 512, LDS_BYTES, stream>>>(xs, xq, tp, (float*)d_out);
}